// Round 1
// baseline (4076.642 us; speedup 1.0000x reference)
//
#include <hip/hip_runtime.h>

// Dims (fixed by the problem)
#define S_LEN 512
#define BATCH 256
#define EMB_D 300
#define EMB_PAD 320
#define HID 128
#define SB (S_LEN*BATCH)   // 131072 rows (time-major m = s*B + b)

typedef __attribute__((ext_vector_type(8))) short bf16x8;   // 8 bf16 = 4 VGPRs
typedef __attribute__((ext_vector_type(4))) float f32x4;
typedef unsigned short u16;
typedef unsigned int   u32;

// ---- bf16 <-> f32 helpers ----
__device__ __forceinline__ float b2f(u16 u) {
    union { u32 i; float f; } v; v.i = ((u32)u) << 16; return v.f;
}
__device__ __forceinline__ u16 f2b(float f) {
    union { float f; u32 i; } v; v.f = f;
    u32 r = v.i + 0x7fffu + ((v.i >> 16) & 1u);   // round-to-nearest-even
    return (u16)(r >> 16);
}
__device__ __forceinline__ float sigf(float x) {
    return __builtin_amdgcn_rcpf(1.f + __expf(-x));
}
__device__ __forceinline__ float tanhf_fast(float x) {
    float e = __expf(2.f * x);
    return 1.f - 2.f * __builtin_amdgcn_rcpf(e + 1.f);
}

// ---- dtype detector: flag=1 if float tensors are bf16, 0 if f32 ----
__global__ void k_detect(const u16* __restrict__ emb_u, int* __restrict__ flag) {
    __shared__ int cnt;
    if (threadIdx.x == 0) cnt = 0;
    __syncthreads();
    float v = b2f(emb_u[2 * threadIdx.x + 64]);
    float a = fabsf(v);
    if (a > 1e-4f && a < 16.f) atomicAdd(&cnt, 1);
    __syncthreads();
    if (threadIdx.x == 0) *flag = (cnt > 128) ? 1 : 0;
}

// ---- weight packing: gate-row permutation row' = 4*j + t (t: 0=i,1=f,2=g,3=o) ----
__global__ void k_packw(const void* __restrict__ src, u16* __restrict__ dst,
                        int Kin, int Kpad, int total, const int* __restrict__ flag) {
    int i = blockIdx.x * 256 + threadIdx.x;
    if (i >= total) return;
    int n = i / Kpad, k = i - n * Kpad;
    int d = n >> 9, r = n & 511, j = r >> 2, t = r & 3;
    size_t si = (size_t)((d << 9) + (t << 7) + j) * Kin + k;
    u16 v = 0;
    if (k < Kin) {
        if (*flag) v = ((const u16*)src)[si];
        else       v = f2b(((const float*)src)[si]);
    }
    dst[i] = v;
}

__global__ void k_packb(const void* __restrict__ src, float* __restrict__ dst,
                        const int* __restrict__ flag) {
    int i = blockIdx.x * 256 + threadIdx.x;
    if (i >= 1024) return;
    int d = i >> 9, r = i & 511, j = r >> 2, t = r & 3;
    size_t si = (d << 9) + (t << 7) + j;
    dst[i] = (*flag) ? b2f(((const u16*)src)[si]) : ((const float*)src)[si];
}

// ---- projection GEMM: C[m,n] = sum_k A[m,k]*W[n,k] + bias[n] ----
template<int KPAD, bool EMBED>
__global__ __launch_bounds__(256) void k_gemm(const int* __restrict__ tok,
                                              const void* __restrict__ Asrc,
                                              const u16* __restrict__ W,
                                              const float* __restrict__ bias,
                                              u16* __restrict__ C,
                                              const int* __restrict__ flag) {
    __shared__ __align__(16) u16 As[64 * 40];   // K-slice 32 padded to 40
    __shared__ __align__(16) u16 Bs[64 * 40];
    const int tid  = threadIdx.x;
    const int m0   = blockIdx.x * 64;
    const int n0   = blockIdx.y * 64;
    const int w    = tid >> 6, lane = tid & 63, quad = lane >> 4, l16 = lane & 15;
    const int mq   = (w >> 1) * 32, nq = (w & 1) * 32;
    const int row  = tid >> 2, seg = tid & 3;

    bool is_bf = true;
    size_t arow_off = 0;
    if constexpr (EMBED) {
        int m = m0 + row, s = m >> 8, b = m & 255;
        is_bf = (*flag != 0);
        arow_off = (size_t)tok[b * S_LEN + s] * EMB_D;
    } else {
        arow_off = (size_t)(m0 + row) * KPAD;
    }
    const u16* brow = W + (size_t)(n0 + row) * KPAD;

    f32x4 acc[2][2] = {};
    const int KSTEPS = KPAD / 32;
#pragma unroll
    for (int kk = 0; kk < KSTEPS; ++kk) {
        uint4 va, vb;
        if constexpr (EMBED) {
            u32 u[4];
            if (is_bf) {
                const u16* arow = (const u16*)Asrc + arow_off;
#pragma unroll
                for (int i = 0; i < 4; ++i) {
                    int c = kk * 32 + seg * 8 + 2 * i;       // even -> 4B aligned pair
                    u[i] = (c < EMB_D) ? *(const u32*)(arow + c) : 0u;
                }
            } else {
                const float* arow = (const float*)Asrc + arow_off;
#pragma unroll
                for (int i = 0; i < 4; ++i) {
                    int c = kk * 32 + seg * 8 + 2 * i;
                    if (c < EMB_D) {
                        float2 f = *(const float2*)(arow + c);
                        u[i] = (u32)f2b(f.x) | ((u32)f2b(f.y) << 16);
                    } else u[i] = 0u;
                }
            }
            va.x = u[0]; va.y = u[1]; va.z = u[2]; va.w = u[3];
        } else {
            va = *((const uint4*)((const u16*)Asrc + arow_off) + kk * 4 + seg);
        }
        vb = *((const uint4*)brow + kk * 4 + seg);
        __syncthreads();
        *(uint4*)(As + row * 40 + seg * 8) = va;
        *(uint4*)(Bs + row * 40 + seg * 8) = vb;
        __syncthreads();
        bf16x8 af[2], bfr[2];
#pragma unroll
        for (int mt = 0; mt < 2; ++mt)
            af[mt] = *(const bf16x8*)(As + (mq + mt * 16 + l16) * 40 + quad * 8);
#pragma unroll
        for (int nt = 0; nt < 2; ++nt)
            bfr[nt] = *(const bf16x8*)(Bs + (nq + nt * 16 + l16) * 40 + quad * 8);
#pragma unroll
        for (int mt = 0; mt < 2; ++mt)
#pragma unroll
            for (int nt = 0; nt < 2; ++nt)
                acc[mt][nt] = __builtin_amdgcn_mfma_f32_16x16x32_bf16(af[mt], bfr[nt], acc[mt][nt], 0, 0, 0);
    }
    // C/D layout: col = lane&15, row = quad*4 + reg  [m89-verified]
#pragma unroll
    for (int mt = 0; mt < 2; ++mt)
#pragma unroll
        for (int nt = 0; nt < 2; ++nt)
#pragma unroll
            for (int r = 0; r < 4; ++r) {
                int m = m0 + mq + mt * 16 + quad * 4 + r;
                int n = n0 + nq + nt * 16 + l16;
                float v = acc[mt][nt][r] + bias[n];
                int d = n >> 9, nn = n & 511;
                C[(size_t)d * SB * 512 + (size_t)m * 512 + nn] = f2b(v);
            }
}

// ---- LSTM recurrence. Block = (dir, 16-batch group); 1024 thr = 16 waves.
// Per-step barrier is lgkmcnt-only (T4): gx prefetch loads and h0seq stores
// stay in flight across the barrier instead of a full vmcnt(0) drain every
// step (was the dominant per-step stall). gx prefetch is 2 steps deep so
// ~900-cycle HBM/L3 latency is covered by ~2 steps of compute.
template<bool IS_L0>
__global__ __launch_bounds__(1024) void k_lstm(const u16* __restrict__ gx, size_t gx_stride,
                                               const u16* __restrict__ Whp, int dir0,
                                               u16* __restrict__ h0seq, float* __restrict__ hT) {
    const int tid  = threadIdx.x;
    const int dl   = blockIdx.x >> 4;
    const int d    = dir0 + dl;
    const int bg   = blockIdx.x & 15;
    const int wv   = tid >> 6, lane = tid & 63, quad = lane >> 4, col = lane & 15;
    const int b    = bg * 16 + col;
    const int mt_base = wv * 2;

    __shared__ __align__(16) u16 hbuf[2][16][136];
    for (int i = tid; i < 2 * 16 * 136; i += 1024) ((u16*)hbuf)[i] = 0;

    // A-frags of W_hh: A[m=lane&15][k=quad*8+j]  [m120-verified]
    const u16* Wd = Whp + (size_t)d * 512 * 128;
    bf16x8 wf[2][4];
#pragma unroll
    for (int mt = 0; mt < 2; ++mt)
#pragma unroll
        for (int ks = 0; ks < 4; ++ks)
            wf[mt][ks] = *(const bf16x8*)(Wd + (size_t)((mt_base + mt) * 16 + col) * 128 + ks * 32 + quad * 8);

    const u16* gxd = gx + (size_t)dl * gx_stride;
    auto gx_ptr = [&](int s, int mt) -> const ushort4* {
        return (const ushort4*)(gxd + ((size_t)s * BATCH + b) * 512 + (size_t)(mt_base + mt) * 16 + quad * 4);
    };
    auto sidx = [&](int si) { return (d == 0) ? si : (S_LEN - 1 - si); };

    float c0 = 0.f, c1 = 0.f;
    __syncthreads();

    // depth-2 prefetch: A holds even-step gx, B holds odd-step gx
    ushort4 pA0 = *gx_ptr(sidx(0), 0);
    ushort4 pA1 = *gx_ptr(sidx(0), 1);
    ushort4 pB0 = *gx_ptr(sidx(1), 0);
    ushort4 pB1 = *gx_ptr(sidx(1), 1);

    auto step = [&](int si, ushort4& p0, ushort4& p1, int curb) {
        const int s = sidx(si);
        f32x4 z0, z1;
        z0[0] = b2f(p0.x); z0[1] = b2f(p0.y); z0[2] = b2f(p0.z); z0[3] = b2f(p0.w);
        z1[0] = b2f(p1.x); z1[1] = b2f(p1.y); z1[2] = b2f(p1.z); z1[3] = b2f(p1.w);
        if (si + 2 < S_LEN) {                 // prefetch 2 steps ahead into same buffer
            int sn = sidx(si + 2);
            p0 = *gx_ptr(sn, 0);
            p1 = *gx_ptr(sn, 1);
        }
        bf16x8 hf[4];
#pragma unroll
        for (int ks = 0; ks < 4; ++ks)
            hf[ks] = *(const bf16x8*)(&hbuf[curb][col][ks * 32 + quad * 8]);
#pragma unroll
        for (int ks = 0; ks < 4; ++ks) {
            z0 = __builtin_amdgcn_mfma_f32_16x16x32_bf16(wf[0][ks], hf[ks], z0, 0, 0, 0);
            z1 = __builtin_amdgcn_mfma_f32_16x16x32_bf16(wf[1][ks], hf[ks], z1, 0, 0, 0);
        }
        float i0 = sigf(z0[0]), f0 = sigf(z0[1]), g0 = tanhf_fast(z0[2]), o0 = sigf(z0[3]);
        c0 = f0 * c0 + i0 * g0;
        float h0v = o0 * tanhf_fast(c0);
        float i1 = sigf(z1[0]), f1 = sigf(z1[1]), g1 = tanhf_fast(z1[2]), o1 = sigf(z1[3]);
        c1 = f1 * c1 + i1 * g1;
        float h1v = o1 * tanhf_fast(c1);

        const int j0 = mt_base * 4 + quad;
        const int j1 = j0 + 4;
        u16 hb0 = f2b(h0v), hb1 = f2b(h1v);
        hbuf[curb ^ 1][col][j0] = hb0;
        hbuf[curb ^ 1][col][j1] = hb1;
        if constexpr (IS_L0) {
            size_t o = ((size_t)s * BATCH + b) * 256 + (d << 7);
            h0seq[o + j0] = hb0;
            h0seq[o + j1] = hb1;
        } else {
            if (si == S_LEN - 1) {
                size_t o = ((size_t)d * BATCH + b) * 128;
                hT[o + j0] = h0v;
                hT[o + j1] = h1v;
            }
        }
        // lgkm-only barrier: hbuf writes visible; vmcnt (gx prefetch + h0seq
        // stores) deliberately NOT drained (T4, m218). Single asm = compiler
        // cannot move LDS ops across it in either direction.
        asm volatile("s_waitcnt lgkmcnt(0)\n\ts_barrier" ::: "memory");
    };

#pragma unroll 1
    for (int si = 0; si < S_LEN; si += 2) {
        step(si,     pA0, pA1, 0);
        step(si + 1, pB0, pB1, 1);
    }
}

// ---- FC head (dtype-flagged weights and output) ----
__global__ void k_fc(const float* __restrict__ hT,
                     const void* __restrict__ fc1w, const void* __restrict__ fc1b,
                     const void* __restrict__ fc2w, const void* __restrict__ fc2b,
                     void* __restrict__ out, const int* __restrict__ flag) {
    int b = blockIdx.x, j = threadIdx.x;
    bool is_bf = (*flag != 0);
    __shared__ float u[128];
    float a = is_bf ? b2f(((const u16*)fc1b)[j]) : ((const float*)fc1b)[j];
    for (int k = 0; k < 256; ++k) {
        float x = hT[((size_t)(k >> 7) * BATCH + b) * 128 + (k & 127)];
        float w = is_bf ? b2f(((const u16*)fc1w)[j * 256 + k]) : ((const float*)fc1w)[j * 256 + k];
        a += x * w;
    }
    u[j] = fmaxf(a, 0.f);
    __syncthreads();
    if (j < 2) {
        float a2 = is_bf ? b2f(((const u16*)fc2b)[j]) : ((const float*)fc2b)[j];
        for (int q = 0; q < 128; ++q) {
            float w = is_bf ? b2f(((const u16*)fc2w)[j * 128 + q]) : ((const float*)fc2w)[j * 128 + q];
            a2 += u[q] * w;
        }
        if (is_bf) ((u16*)out)[b * 2 + j] = f2b(a2);
        else       ((float*)out)[b * 2 + j] = a2;
    }
}

extern "C" void kernel_launch(void* const* d_in, const int* in_sizes, int n_in,
                              void* d_out, int out_size, void* d_ws, size_t ws_size,
                              hipStream_t stream) {
    const int*  tok   = (const int*)d_in[0];
    const void* emb   = d_in[1];
    const void* w_ih0 = d_in[2];
    const void* w_hh0 = d_in[3];
    const void* b0    = d_in[4];
    const void* w_ih1 = d_in[5];
    const void* w_hh1 = d_in[6];
    const void* b1    = d_in[7];
    const void* fc1w  = d_in[8];
    const void* fc1b  = d_in[9];
    const void* fc2w  = d_in[10];
    const void* fc2b  = d_in[11];

    char* ws = (char*)d_ws;
    size_t off = 0;
    auto alloc = [&](size_t bytes) -> void* {
        void* p = ws + off; off += (bytes + 255) & ~(size_t)255; return p;
    };
    int*   flag  = (int*)alloc(256);
    u16*   Wp0   = (u16*)alloc(1024 * 320 * 2);
    u16*   Wp1   = (u16*)alloc(1024 * 256 * 2);
    u16*   Whp0  = (u16*)alloc(1024 * 128 * 2);
    u16*   Whp1  = (u16*)alloc(1024 * 128 * 2);
    float* bp0   = (float*)alloc(1024 * 4);
    float* bp1   = (float*)alloc(1024 * 4);
    float* hT    = (float*)alloc((size_t)2 * BATCH * 128 * 4);
    u16*   h0seq = (u16*)alloc((size_t)SB * 256 * 2);            // 64 MiB
    size_t gx1   = (size_t)SB * 512 * 2;                         // one dir: 128 MiB
    bool   big   = ws_size >= off + 2 * gx1;                     // both dirs resident?
    u16*   gx    = (u16*)alloc(big ? 2 * gx1 : gx1);

    k_detect<<<1, 256, 0, stream>>>((const u16*)emb, flag);

    k_packw<<<(1024 * 320 + 255) / 256, 256, 0, stream>>>(w_ih0, Wp0, 300, 320, 1024 * 320, flag);
    k_packw<<<(1024 * 256 + 255) / 256, 256, 0, stream>>>(w_ih1, Wp1, 256, 256, 1024 * 256, flag);
    k_packw<<<(1024 * 128 + 255) / 256, 256, 0, stream>>>(w_hh0, Whp0, 128, 128, 1024 * 128, flag);
    k_packw<<<(1024 * 128 + 255) / 256, 256, 0, stream>>>(w_hh1, Whp1, 128, 128, 1024 * 128, flag);
    k_packb<<<4, 256, 0, stream>>>(b0, bp0, flag);
    k_packb<<<4, 256, 0, stream>>>(b1, bp1, flag);

    if (big) {
        dim3 g(SB / 64, 16);
        k_gemm<320, true ><<<g, 256, 0, stream>>>(tok, emb, Wp0, bp0, gx, flag);
        k_lstm<true ><<<32, 1024, 0, stream>>>(gx, (size_t)SB * 512, Whp0, 0, h0seq, nullptr);
        k_gemm<256, false><<<g, 256, 0, stream>>>(nullptr, h0seq, Wp1, bp1, gx, flag);
        k_lstm<false><<<32, 1024, 0, stream>>>(gx, (size_t)SB * 512, Whp1, 0, nullptr, hT);
    } else {
        dim3 g(SB / 64, 8);   // one direction's 512 gate columns
        for (int d = 0; d < 2; ++d) {
            k_gemm<320, true ><<<g, 256, 0, stream>>>(tok, emb, Wp0 + (size_t)d * 512 * 320, bp0 + d * 512, gx, flag);
            k_lstm<true ><<<16, 1024, 0, stream>>>(gx, 0, Whp0, d, h0seq, nullptr);
        }
        for (int d = 0; d < 2; ++d) {
            k_gemm<256, false><<<g, 256, 0, stream>>>(nullptr, h0seq, Wp1 + (size_t)d * 512 * 256, bp1 + d * 512, gx, flag);
            k_lstm<false><<<16, 1024, 0, stream>>>(gx, 0, Whp1, d, nullptr, hT);
        }
    }
    k_fc<<<256, 128, 0, stream>>>(hT, fc1w, fc1b, fc2w, fc2b, d_out, flag);
}

// Round 2
// 3044.836 us; speedup vs baseline: 1.3389x; 1.3389x over previous
//
#include <hip/hip_runtime.h>

// Dims (fixed by the problem)
#define S_LEN 512
#define BATCH 256
#define EMB_D 300
#define EMB_PAD 320
#define HID 128
#define SB (S_LEN*BATCH)   // 131072 rows (time-major m = s*B + b)

typedef __attribute__((ext_vector_type(8))) short bf16x8;   // 8 bf16 = 4 VGPRs
typedef __attribute__((ext_vector_type(4))) float f32x4;
typedef unsigned short u16;
typedef unsigned int   u32;

// ---- bf16 <-> f32 helpers ----
__device__ __forceinline__ float b2f(u16 u) {
    union { u32 i; float f; } v; v.i = ((u32)u) << 16; return v.f;
}
__device__ __forceinline__ u16 f2b(float f) {
    union { float f; u32 i; } v; v.f = f;
    u32 r = v.i + 0x7fffu + ((v.i >> 16) & 1u);   // round-to-nearest-even
    return (u16)(r >> 16);
}
__device__ __forceinline__ float sigf(float x) {
    return __builtin_amdgcn_rcpf(1.f + __expf(-x));
}
__device__ __forceinline__ float tanhf_fast(float x) {
    float e = __expf(2.f * x);
    return 1.f - 2.f * __builtin_amdgcn_rcpf(e + 1.f);
}

// ---- dtype detector: flag=1 if float tensors are bf16, 0 if f32 ----
__global__ void k_detect(const u16* __restrict__ emb_u, int* __restrict__ flag) {
    __shared__ int cnt;
    if (threadIdx.x == 0) cnt = 0;
    __syncthreads();
    float v = b2f(emb_u[2 * threadIdx.x + 64]);
    float a = fabsf(v);
    if (a > 1e-4f && a < 16.f) atomicAdd(&cnt, 1);
    __syncthreads();
    if (threadIdx.x == 0) *flag = (cnt > 128) ? 1 : 0;
}

// ---- weight packing: gate-row permutation row' = 4*j + t (t: 0=i,1=f,2=g,3=o) ----
__global__ void k_packw(const void* __restrict__ src, u16* __restrict__ dst,
                        int Kin, int Kpad, int total, const int* __restrict__ flag) {
    int i = blockIdx.x * 256 + threadIdx.x;
    if (i >= total) return;
    int n = i / Kpad, k = i - n * Kpad;
    int d = n >> 9, r = n & 511, j = r >> 2, t = r & 3;
    size_t si = (size_t)((d << 9) + (t << 7) + j) * Kin + k;
    u16 v = 0;
    if (k < Kin) {
        if (*flag) v = ((const u16*)src)[si];
        else       v = f2b(((const float*)src)[si]);
    }
    dst[i] = v;
}

__global__ void k_packb(const void* __restrict__ src, float* __restrict__ dst,
                        const int* __restrict__ flag) {
    int i = blockIdx.x * 256 + threadIdx.x;
    if (i >= 1024) return;
    int d = i >> 9, r = i & 511, j = r >> 2, t = r & 3;
    size_t si = (d << 9) + (t << 7) + j;
    dst[i] = (*flag) ? b2f(((const u16*)src)[si]) : ((const float*)src)[si];
}

// ---- projection GEMM: C[m,n] = sum_k A[m,k]*W[n,k] + bias[n] ----
template<int KPAD, bool EMBED>
__global__ __launch_bounds__(256) void k_gemm(const int* __restrict__ tok,
                                              const void* __restrict__ Asrc,
                                              const u16* __restrict__ W,
                                              const float* __restrict__ bias,
                                              u16* __restrict__ C,
                                              const int* __restrict__ flag) {
    __shared__ __align__(16) u16 As[64 * 40];   // K-slice 32 padded to 40
    __shared__ __align__(16) u16 Bs[64 * 40];
    const int tid  = threadIdx.x;
    const int m0   = blockIdx.x * 64;
    const int n0   = blockIdx.y * 64;
    const int w    = tid >> 6, lane = tid & 63, quad = lane >> 4, l16 = lane & 15;
    const int mq   = (w >> 1) * 32, nq = (w & 1) * 32;
    const int row  = tid >> 2, seg = tid & 3;

    bool is_bf = true;
    size_t arow_off = 0;
    if constexpr (EMBED) {
        int m = m0 + row, s = m >> 8, b = m & 255;
        is_bf = (*flag != 0);
        arow_off = (size_t)tok[b * S_LEN + s] * EMB_D;
    } else {
        arow_off = (size_t)(m0 + row) * KPAD;
    }
    const u16* brow = W + (size_t)(n0 + row) * KPAD;

    f32x4 acc[2][2] = {};
    const int KSTEPS = KPAD / 32;
#pragma unroll
    for (int kk = 0; kk < KSTEPS; ++kk) {
        uint4 va, vb;
        if constexpr (EMBED) {
            u32 u[4];
            if (is_bf) {
                const u16* arow = (const u16*)Asrc + arow_off;
#pragma unroll
                for (int i = 0; i < 4; ++i) {
                    int c = kk * 32 + seg * 8 + 2 * i;       // even -> 4B aligned pair
                    u[i] = (c < EMB_D) ? *(const u32*)(arow + c) : 0u;
                }
            } else {
                const float* arow = (const float*)Asrc + arow_off;
#pragma unroll
                for (int i = 0; i < 4; ++i) {
                    int c = kk * 32 + seg * 8 + 2 * i;
                    if (c < EMB_D) {
                        float2 f = *(const float2*)(arow + c);
                        u[i] = (u32)f2b(f.x) | ((u32)f2b(f.y) << 16);
                    } else u[i] = 0u;
                }
            }
            va.x = u[0]; va.y = u[1]; va.z = u[2]; va.w = u[3];
        } else {
            va = *((const uint4*)((const u16*)Asrc + arow_off) + kk * 4 + seg);
        }
        vb = *((const uint4*)brow + kk * 4 + seg);
        __syncthreads();
        *(uint4*)(As + row * 40 + seg * 8) = va;
        *(uint4*)(Bs + row * 40 + seg * 8) = vb;
        __syncthreads();
        bf16x8 af[2], bfr[2];
#pragma unroll
        for (int mt = 0; mt < 2; ++mt)
            af[mt] = *(const bf16x8*)(As + (mq + mt * 16 + l16) * 40 + quad * 8);
#pragma unroll
        for (int nt = 0; nt < 2; ++nt)
            bfr[nt] = *(const bf16x8*)(Bs + (nq + nt * 16 + l16) * 40 + quad * 8);
#pragma unroll
        for (int mt = 0; mt < 2; ++mt)
#pragma unroll
            for (int nt = 0; nt < 2; ++nt)
                acc[mt][nt] = __builtin_amdgcn_mfma_f32_16x16x32_bf16(af[mt], bfr[nt], acc[mt][nt], 0, 0, 0);
    }
    // C/D layout: col = lane&15, row = quad*4 + reg  [m89-verified]
#pragma unroll
    for (int mt = 0; mt < 2; ++mt)
#pragma unroll
        for (int nt = 0; nt < 2; ++nt)
#pragma unroll
            for (int r = 0; r < 4; ++r) {
                int m = m0 + mq + mt * 16 + quad * 4 + r;
                int n = n0 + nq + nt * 16 + l16;
                float v = acc[mt][nt][r] + bias[n];
                int d = n >> 9, nn = n & 511;
                C[(size_t)d * SB * 512 + (size_t)m * 512 + nn] = f2b(v);
            }
}

// ---- LSTM recurrence. Block = (dir, 16-batch group); 512 thr = 8 waves.
// Wave wv owns gate tiles wv*4..wv*4+3 (64 gate rows) x 16 batches -> 16 MFMAs,
// 4 h per thread. gx staged through LDS via global_load_lds (dense 1KB rows,
// double-buffered); h0seq stored from hbuf as dense 256B runs (prev step's h,
// post-barrier). Targets vmem segment/TA contention (round-2 theory).
template<bool IS_L0>
__global__ __launch_bounds__(512) void k_lstm(const u16* __restrict__ gx, size_t gx_stride,
                                              const u16* __restrict__ Whp, int dir0,
                                              u16* __restrict__ h0seq, float* __restrict__ hT) {
    const int tid  = threadIdx.x;
    const int dl   = blockIdx.x >> 4;
    const int d    = dir0 + dl;
    const int bg   = blockIdx.x & 15;
    const int wv   = tid >> 6, lane = tid & 63, quad = lane >> 4, col = lane & 15;

    __shared__ __align__(16) u16 hbuf[2][16][136];   // [buf][b-local][h j], padded
    __shared__ __align__(16) u16 gxb [2][16][520];   // [buf][b-local][512 gates], padded

    for (int i = tid; i < 2 * 16 * 136; i += 512) ((u16*)hbuf)[i] = 0;

    // A-frags of W_hh: A[m=lane&15][k=quad*8+j]  [m120-verified]
    const u16* Wd = Whp + (size_t)d * 512 * 128;
    bf16x8 wf[4][4];
#pragma unroll
    for (int mt = 0; mt < 4; ++mt)
#pragma unroll
        for (int ks = 0; ks < 4; ++ks)
            wf[mt][ks] = *(const bf16x8*)(Wd + (size_t)((wv * 4 + mt) * 16 + col) * 128 + ks * 32 + quad * 8);

    const u16* gxd = gx + (size_t)dl * gx_stride;
    auto sidx = [&](int si) { return (d == 0) ? si : (S_LEN - 1 - si); };

    const int r0 = 2 * wv;                      // wave's two b-local rows
    auto prefetch = [&](int s, int P) {
        const u16* g0 = gxd + ((size_t)s * BATCH + bg * 16 + r0) * 512 + lane * 8;
        const u16* g1 = g0 + 512;
        __builtin_amdgcn_global_load_lds((const __attribute__((address_space(1))) void*)g0,
            (__attribute__((address_space(3))) void*)&gxb[P][r0][0], 16, 0, 0);
        __builtin_amdgcn_global_load_lds((const __attribute__((address_space(1))) void*)g1,
            (__attribute__((address_space(3))) void*)&gxb[P][r0 + 1][0], 16, 0, 0);
    };

    float c[4] = {0.f, 0.f, 0.f, 0.f};

    auto step = [&](int si, int P) {            // P = si & 1 (literal at call sites)
        if (si + 1 < S_LEN) prefetch(sidx(si + 1), P ^ 1);
        if constexpr (IS_L0) {
            if (si > 0) {                        // store PREV step's h (published by barrier)
                int sp = sidx(si - 1);
                int bl = r0 + (lane >> 5);
                int j4 = (lane & 31) * 4;
                ushort4 hv = *(const ushort4*)&hbuf[P][bl][j4];
                *(ushort4*)(h0seq + ((size_t)sp * BATCH + bg * 16 + bl) * 256 + (d << 7) + j4) = hv;
            }
        }
        bf16x8 hf[4];
#pragma unroll
        for (int ks = 0; ks < 4; ++ks)
            hf[ks] = *(const bf16x8*)&hbuf[P][col][ks * 32 + quad * 8];
        f32x4 z[4];
#pragma unroll
        for (int mt = 0; mt < 4; ++mt) {
            ushort4 gv = *(const ushort4*)&gxb[P][col][wv * 64 + mt * 16 + quad * 4];
            z[mt][0] = b2f(gv.x); z[mt][1] = b2f(gv.y); z[mt][2] = b2f(gv.z); z[mt][3] = b2f(gv.w);
        }
#pragma unroll
        for (int ks = 0; ks < 4; ++ks)
#pragma unroll
            for (int mt = 0; mt < 4; ++mt)
                z[mt] = __builtin_amdgcn_mfma_f32_16x16x32_bf16(wf[mt][ks], hf[ks], z[mt], 0, 0, 0);
#pragma unroll
        for (int mt = 0; mt < 4; ++mt) {
            float iv = sigf(z[mt][0]), fv = sigf(z[mt][1]);
            float gg = tanhf_fast(z[mt][2]), ov = sigf(z[mt][3]);
            c[mt] = fv * c[mt] + iv * gg;
            float hv = ov * tanhf_fast(c[mt]);
            hbuf[P ^ 1][col][wv * 16 + mt * 4 + quad] = f2b(hv);
            if constexpr (!IS_L0) {
                if (si == S_LEN - 1)
                    hT[((size_t)d * BATCH + bg * 16 + col) * 128 + wv * 16 + mt * 4 + quad] = hv;
            }
        }
        __syncthreads();
    };

    prefetch(sidx(0), 0);
    __syncthreads();                            // hbuf zeros + gx(s0) visible

    for (int si = 0; si < S_LEN; si += 2) {
        step(si, 0);
        step(si + 1, 1);
    }

    if constexpr (IS_L0) {                      // final step's h (in hbuf[0])
        int sp = sidx(S_LEN - 1);
        int bl = r0 + (lane >> 5);
        int j4 = (lane & 31) * 4;
        ushort4 hv = *(const ushort4*)&hbuf[0][bl][j4];
        *(ushort4*)(h0seq + ((size_t)sp * BATCH + bg * 16 + bl) * 256 + (d << 7) + j4) = hv;
    }
}

// ---- FC head (dtype-flagged weights and output) ----
__global__ void k_fc(const float* __restrict__ hT,
                     const void* __restrict__ fc1w, const void* __restrict__ fc1b,
                     const void* __restrict__ fc2w, const void* __restrict__ fc2b,
                     void* __restrict__ out, const int* __restrict__ flag) {
    int b = blockIdx.x, j = threadIdx.x;
    bool is_bf = (*flag != 0);
    __shared__ float u[128];
    float a = is_bf ? b2f(((const u16*)fc1b)[j]) : ((const float*)fc1b)[j];
    for (int k = 0; k < 256; ++k) {
        float x = hT[((size_t)(k >> 7) * BATCH + b) * 128 + (k & 127)];
        float w = is_bf ? b2f(((const u16*)fc1w)[j * 256 + k]) : ((const float*)fc1w)[j * 256 + k];
        a += x * w;
    }
    u[j] = fmaxf(a, 0.f);
    __syncthreads();
    if (j < 2) {
        float a2 = is_bf ? b2f(((const u16*)fc2b)[j]) : ((const float*)fc2b)[j];
        for (int q = 0; q < 128; ++q) {
            float w = is_bf ? b2f(((const u16*)fc2w)[j * 128 + q]) : ((const float*)fc2w)[j * 128 + q];
            a2 += u[q] * w;
        }
        if (is_bf) ((u16*)out)[b * 2 + j] = f2b(a2);
        else       ((float*)out)[b * 2 + j] = a2;
    }
}

extern "C" void kernel_launch(void* const* d_in, const int* in_sizes, int n_in,
                              void* d_out, int out_size, void* d_ws, size_t ws_size,
                              hipStream_t stream) {
    const int*  tok   = (const int*)d_in[0];
    const void* emb   = d_in[1];
    const void* w_ih0 = d_in[2];
    const void* w_hh0 = d_in[3];
    const void* b0    = d_in[4];
    const void* w_ih1 = d_in[5];
    const void* w_hh1 = d_in[6];
    const void* b1    = d_in[7];
    const void* fc1w  = d_in[8];
    const void* fc1b  = d_in[9];
    const void* fc2w  = d_in[10];
    const void* fc2b  = d_in[11];

    char* ws = (char*)d_ws;
    size_t off = 0;
    auto alloc = [&](size_t bytes) -> void* {
        void* p = ws + off; off += (bytes + 255) & ~(size_t)255; return p;
    };
    int*   flag  = (int*)alloc(256);
    u16*   Wp0   = (u16*)alloc(1024 * 320 * 2);
    u16*   Wp1   = (u16*)alloc(1024 * 256 * 2);
    u16*   Whp0  = (u16*)alloc(1024 * 128 * 2);
    u16*   Whp1  = (u16*)alloc(1024 * 128 * 2);
    float* bp0   = (float*)alloc(1024 * 4);
    float* bp1   = (float*)alloc(1024 * 4);
    float* hT    = (float*)alloc((size_t)2 * BATCH * 128 * 4);
    u16*   h0seq = (u16*)alloc((size_t)SB * 256 * 2);            // 64 MiB
    size_t gx1   = (size_t)SB * 512 * 2;                         // one dir: 128 MiB
    bool   big   = ws_size >= off + 2 * gx1;                     // both dirs resident?
    u16*   gx    = (u16*)alloc(big ? 2 * gx1 : gx1);

    k_detect<<<1, 256, 0, stream>>>((const u16*)emb, flag);

    k_packw<<<(1024 * 320 + 255) / 256, 256, 0, stream>>>(w_ih0, Wp0, 300, 320, 1024 * 320, flag);
    k_packw<<<(1024 * 256 + 255) / 256, 256, 0, stream>>>(w_ih1, Wp1, 256, 256, 1024 * 256, flag);
    k_packw<<<(1024 * 128 + 255) / 256, 256, 0, stream>>>(w_hh0, Whp0, 128, 128, 1024 * 128, flag);
    k_packw<<<(1024 * 128 + 255) / 256, 256, 0, stream>>>(w_hh1, Whp1, 128, 128, 1024 * 128, flag);
    k_packb<<<4, 256, 0, stream>>>(b0, bp0, flag);
    k_packb<<<4, 256, 0, stream>>>(b1, bp1, flag);

    if (big) {
        dim3 g(SB / 64, 16);
        k_gemm<320, true ><<<g, 256, 0, stream>>>(tok, emb, Wp0, bp0, gx, flag);
        k_lstm<true ><<<32, 512, 0, stream>>>(gx, (size_t)SB * 512, Whp0, 0, h0seq, nullptr);
        k_gemm<256, false><<<g, 256, 0, stream>>>(nullptr, h0seq, Wp1, bp1, gx, flag);
        k_lstm<false><<<32, 512, 0, stream>>>(gx, (size_t)SB * 512, Whp1, 0, nullptr, hT);
    } else {
        dim3 g(SB / 64, 8);   // one direction's 512 gate columns
        for (int d = 0; d < 2; ++d) {
            k_gemm<320, true ><<<g, 256, 0, stream>>>(tok, emb, Wp0 + (size_t)d * 512 * 320, bp0 + d * 512, gx, flag);
            k_lstm<true ><<<16, 512, 0, stream>>>(gx, 0, Whp0, d, h0seq, nullptr);
        }
        for (int d = 0; d < 2; ++d) {
            k_gemm<256, false><<<g, 256, 0, stream>>>(nullptr, h0seq, Wp1 + (size_t)d * 512 * 256, bp1 + d * 512, gx, flag);
            k_lstm<false><<<16, 512, 0, stream>>>(gx, 0, Whp1, d, nullptr, hT);
        }
    }
    k_fc<<<256, 128, 0, stream>>>(hT, fc1w, fc1b, fc2w, fc2b, d_out, flag);
}

// Round 3
// 3017.468 us; speedup vs baseline: 1.3510x; 1.0091x over previous
//
#include <hip/hip_runtime.h>

// Dims (fixed by the problem)
#define S_LEN 512
#define BATCH 256
#define EMB_D 300
#define EMB_PAD 320
#define HID 128
#define SB (S_LEN*BATCH)   // 131072 rows (time-major m = s*B + b)

typedef __attribute__((ext_vector_type(8))) short bf16x8;   // 8 bf16 = 4 VGPRs
typedef __attribute__((ext_vector_type(4))) float f32x4;
typedef unsigned short u16;
typedef unsigned int   u32;

// ---- bf16 <-> f32 helpers ----
__device__ __forceinline__ float b2f(u16 u) {
    union { u32 i; float f; } v; v.i = ((u32)u) << 16; return v.f;
}
__device__ __forceinline__ u16 f2b(float f) {
    union { float f; u32 i; } v; v.f = f;
    u32 r = v.i + 0x7fffu + ((v.i >> 16) & 1u);   // round-to-nearest-even
    return (u16)(r >> 16);
}
__device__ __forceinline__ float sigf(float x) {
    return __builtin_amdgcn_rcpf(1.f + __expf(-x));
}
__device__ __forceinline__ float tanhf_fast(float x) {
    float e = __expf(2.f * x);
    return 1.f - 2.f * __builtin_amdgcn_rcpf(e + 1.f);
}

// ---- dtype detector: flag=1 if float tensors are bf16, 0 if f32 ----
__global__ void k_detect(const u16* __restrict__ emb_u, int* __restrict__ flag) {
    __shared__ int cnt;
    if (threadIdx.x == 0) cnt = 0;
    __syncthreads();
    float v = b2f(emb_u[2 * threadIdx.x + 64]);
    float a = fabsf(v);
    if (a > 1e-4f && a < 16.f) atomicAdd(&cnt, 1);
    __syncthreads();
    if (threadIdx.x == 0) *flag = (cnt > 128) ? 1 : 0;
}

// ---- weight packing: gate-row permutation row' = 4*j + t (t: 0=i,1=f,2=g,3=o) ----
__global__ void k_packw(const void* __restrict__ src, u16* __restrict__ dst,
                        int Kin, int Kpad, int total, const int* __restrict__ flag) {
    int i = blockIdx.x * 256 + threadIdx.x;
    if (i >= total) return;
    int n = i / Kpad, k = i - n * Kpad;
    int d = n >> 9, r = n & 511, j = r >> 2, t = r & 3;
    size_t si = (size_t)((d << 9) + (t << 7) + j) * Kin + k;
    u16 v = 0;
    if (k < Kin) {
        if (*flag) v = ((const u16*)src)[si];
        else       v = f2b(((const float*)src)[si]);
    }
    dst[i] = v;
}

__global__ void k_packb(const void* __restrict__ src, float* __restrict__ dst,
                        const int* __restrict__ flag) {
    int i = blockIdx.x * 256 + threadIdx.x;
    if (i >= 1024) return;
    int d = i >> 9, r = i & 511, j = r >> 2, t = r & 3;
    size_t si = (d << 9) + (t << 7) + j;
    dst[i] = (*flag) ? b2f(((const u16*)src)[si]) : ((const float*)src)[si];
}

// ---- projection GEMM: C[m,n] = sum_k A[m,k]*W[n,k] + bias[n] ----
template<int KPAD, bool EMBED>
__global__ __launch_bounds__(256) void k_gemm(const int* __restrict__ tok,
                                              const void* __restrict__ Asrc,
                                              const u16* __restrict__ W,
                                              const float* __restrict__ bias,
                                              u16* __restrict__ C,
                                              const int* __restrict__ flag) {
    __shared__ __align__(16) u16 As[64 * 40];   // K-slice 32 padded to 40
    __shared__ __align__(16) u16 Bs[64 * 40];
    const int tid  = threadIdx.x;
    const int m0   = blockIdx.x * 64;
    const int n0   = blockIdx.y * 64;
    const int w    = tid >> 6, lane = tid & 63, quad = lane >> 4, l16 = lane & 15;
    const int mq   = (w >> 1) * 32, nq = (w & 1) * 32;
    const int row  = tid >> 2, seg = tid & 3;

    bool is_bf = true;
    size_t arow_off = 0;
    if constexpr (EMBED) {
        int m = m0 + row, s = m >> 8, b = m & 255;
        is_bf = (*flag != 0);
        arow_off = (size_t)tok[b * S_LEN + s] * EMB_D;
    } else {
        arow_off = (size_t)(m0 + row) * KPAD;
    }
    const u16* brow = W + (size_t)(n0 + row) * KPAD;

    f32x4 acc[2][2] = {};
    const int KSTEPS = KPAD / 32;
#pragma unroll
    for (int kk = 0; kk < KSTEPS; ++kk) {
        uint4 va, vb;
        if constexpr (EMBED) {
            u32 u[4];
            if (is_bf) {
                const u16* arow = (const u16*)Asrc + arow_off;
#pragma unroll
                for (int i = 0; i < 4; ++i) {
                    int c = kk * 32 + seg * 8 + 2 * i;       // even -> 4B aligned pair
                    u[i] = (c < EMB_D) ? *(const u32*)(arow + c) : 0u;
                }
            } else {
                const float* arow = (const float*)Asrc + arow_off;
#pragma unroll
                for (int i = 0; i < 4; ++i) {
                    int c = kk * 32 + seg * 8 + 2 * i;
                    if (c < EMB_D) {
                        float2 f = *(const float2*)(arow + c);
                        u[i] = (u32)f2b(f.x) | ((u32)f2b(f.y) << 16);
                    } else u[i] = 0u;
                }
            }
            va.x = u[0]; va.y = u[1]; va.z = u[2]; va.w = u[3];
        } else {
            va = *((const uint4*)((const u16*)Asrc + arow_off) + kk * 4 + seg);
        }
        vb = *((const uint4*)brow + kk * 4 + seg);
        __syncthreads();
        *(uint4*)(As + row * 40 + seg * 8) = va;
        *(uint4*)(Bs + row * 40 + seg * 8) = vb;
        __syncthreads();
        bf16x8 af[2], bfr[2];
#pragma unroll
        for (int mt = 0; mt < 2; ++mt)
            af[mt] = *(const bf16x8*)(As + (mq + mt * 16 + l16) * 40 + quad * 8);
#pragma unroll
        for (int nt = 0; nt < 2; ++nt)
            bfr[nt] = *(const bf16x8*)(Bs + (nq + nt * 16 + l16) * 40 + quad * 8);
#pragma unroll
        for (int mt = 0; mt < 2; ++mt)
#pragma unroll
            for (int nt = 0; nt < 2; ++nt)
                acc[mt][nt] = __builtin_amdgcn_mfma_f32_16x16x32_bf16(af[mt], bfr[nt], acc[mt][nt], 0, 0, 0);
    }
    // C/D layout: col = lane&15, row = quad*4 + reg  [m89-verified]
#pragma unroll
    for (int mt = 0; mt < 2; ++mt)
#pragma unroll
        for (int nt = 0; nt < 2; ++nt)
#pragma unroll
            for (int r = 0; r < 4; ++r) {
                int m = m0 + mq + mt * 16 + quad * 4 + r;
                int n = n0 + nq + nt * 16 + l16;
                float v = acc[mt][nt][r] + bias[n];
                int d = n >> 9, nn = n & 511;
                C[(size_t)d * SB * 512 + (size_t)m * 512 + nn] = f2b(v);
            }
}

// ---- LSTM recurrence. Block = (dir, 16-batch group); 1024 thr = 16 waves,
// 4 waves/SIMD (was 8 waves / 2 per SIMD). Wave wv owns gate tiles wv*2,
// wv*2+1 (32 gate rows) x 16 batches -> 8 MFMAs, 2 h per thread. Same issue
// count per SIMD as the 8-wave version, but 2x the resident waves to hide
// trans/LDS/MFMA latency (round-2 counters: ~50% of step time was stall).
// gx staged through LDS via global_load_lds (1 dense 1KB row per wave,
// double-buffered); h0seq stored as dense 256B runs (prev step's h).
template<bool IS_L0>
__global__ __launch_bounds__(1024) void k_lstm(const u16* __restrict__ gx, size_t gx_stride,
                                               const u16* __restrict__ Whp, int dir0,
                                               u16* __restrict__ h0seq, float* __restrict__ hT) {
    const int tid  = threadIdx.x;
    const int dl   = blockIdx.x >> 4;
    const int d    = dir0 + dl;
    const int bg   = blockIdx.x & 15;
    const int wv   = tid >> 6, lane = tid & 63, quad = lane >> 4, col = lane & 15;

    __shared__ __align__(16) u16 hbuf[2][16][136];   // [buf][b-local][h j], padded
    __shared__ __align__(16) u16 gxb [2][16][520];   // [buf][b-local][512 gates], padded

    for (int i = tid; i < 2 * 16 * 136; i += 1024) ((u16*)hbuf)[i] = 0;

    // A-frags of W_hh: A[m=lane&15][k=quad*8+j]  [m120-verified]
    const u16* Wd = Whp + (size_t)d * 512 * 128;
    bf16x8 wf[2][4];
#pragma unroll
    for (int mt = 0; mt < 2; ++mt)
#pragma unroll
        for (int ks = 0; ks < 4; ++ks)
            wf[mt][ks] = *(const bf16x8*)(Wd + (size_t)(((wv * 2 + mt) * 16) + col) * 128 + ks * 32 + quad * 8);

    const u16* gxd = gx + (size_t)dl * gx_stride;
    auto sidx = [&](int si) { return (d == 0) ? si : (S_LEN - 1 - si); };

    // wave wv DMAs one dense 1KB gx row (batch-local row wv) per step
    auto prefetch = [&](int s, int P) {
        const u16* g0 = gxd + ((size_t)s * BATCH + bg * 16 + wv) * 512 + lane * 8;
        __builtin_amdgcn_global_load_lds((const __attribute__((address_space(1))) void*)g0,
            (__attribute__((address_space(3))) void*)&gxb[P][wv][0], 16, 0, 0);
    };

    float c[2] = {0.f, 0.f};

    auto step = [&](int si, int P) {            // P = si & 1 (literal at call sites)
        if (si + 1 < S_LEN) prefetch(sidx(si + 1), P ^ 1);
        if constexpr (IS_L0) {
            if (si > 0) {                        // store PREV step's h (published by barrier)
                int sp = sidx(si - 1);
                ushort2 hv = *(const ushort2*)&hbuf[P][wv][lane * 2];
                *(ushort2*)(h0seq + ((size_t)sp * BATCH + bg * 16 + wv) * 256 + (d << 7) + lane * 2) = hv;
            }
        }
        bf16x8 hf[4];
#pragma unroll
        for (int ks = 0; ks < 4; ++ks)
            hf[ks] = *(const bf16x8*)&hbuf[P][col][ks * 32 + quad * 8];
        f32x4 z[2];
#pragma unroll
        for (int mt = 0; mt < 2; ++mt) {
            ushort4 gv = *(const ushort4*)&gxb[P][col][(wv * 2 + mt) * 16 + quad * 4];
            z[mt][0] = b2f(gv.x); z[mt][1] = b2f(gv.y); z[mt][2] = b2f(gv.z); z[mt][3] = b2f(gv.w);
        }
#pragma unroll
        for (int ks = 0; ks < 4; ++ks)
#pragma unroll
            for (int mt = 0; mt < 2; ++mt)
                z[mt] = __builtin_amdgcn_mfma_f32_16x16x32_bf16(wf[mt][ks], hf[ks], z[mt], 0, 0, 0);
#pragma unroll
        for (int mt = 0; mt < 2; ++mt) {
            float iv = sigf(z[mt][0]), fv = sigf(z[mt][1]);
            float gg = tanhf_fast(z[mt][2]), ov = sigf(z[mt][3]);
            c[mt] = fv * c[mt] + iv * gg;
            float hv = ov * tanhf_fast(c[mt]);
            const int j = (wv * 2 + mt) * 4 + quad;          // hidden-unit index
            hbuf[P ^ 1][col][j] = f2b(hv);
            if constexpr (!IS_L0) {
                if (si == S_LEN - 1)
                    hT[((size_t)d * BATCH + bg * 16 + col) * 128 + j] = hv;
            }
        }
        __syncthreads();
    };

    prefetch(sidx(0), 0);
    __syncthreads();                            // hbuf zeros + gx(s0) visible

    for (int si = 0; si < S_LEN; si += 2) {
        step(si, 0);
        step(si + 1, 1);
    }

    if constexpr (IS_L0) {                      // final step's h (in hbuf[0])
        int sp = sidx(S_LEN - 1);
        ushort2 hv = *(const ushort2*)&hbuf[0][wv][lane * 2];
        *(ushort2*)(h0seq + ((size_t)sp * BATCH + bg * 16 + wv) * 256 + (d << 7) + lane * 2) = hv;
    }
}

// ---- FC head (dtype-flagged weights and output) ----
__global__ void k_fc(const float* __restrict__ hT,
                     const void* __restrict__ fc1w, const void* __restrict__ fc1b,
                     const void* __restrict__ fc2w, const void* __restrict__ fc2b,
                     void* __restrict__ out, const int* __restrict__ flag) {
    int b = blockIdx.x, j = threadIdx.x;
    bool is_bf = (*flag != 0);
    __shared__ float u[128];
    float a = is_bf ? b2f(((const u16*)fc1b)[j]) : ((const float*)fc1b)[j];
    for (int k = 0; k < 256; ++k) {
        float x = hT[((size_t)(k >> 7) * BATCH + b) * 128 + (k & 127)];
        float w = is_bf ? b2f(((const u16*)fc1w)[j * 256 + k]) : ((const float*)fc1w)[j * 256 + k];
        a += x * w;
    }
    u[j] = fmaxf(a, 0.f);
    __syncthreads();
    if (j < 2) {
        float a2 = is_bf ? b2f(((const u16*)fc2b)[j]) : ((const float*)fc2b)[j];
        for (int q = 0; q < 128; ++q) {
            float w = is_bf ? b2f(((const u16*)fc2w)[j * 128 + q]) : ((const float*)fc2w)[j * 128 + q];
            a2 += u[q] * w;
        }
        if (is_bf) ((u16*)out)[b * 2 + j] = f2b(a2);
        else       ((float*)out)[b * 2 + j] = a2;
    }
}

extern "C" void kernel_launch(void* const* d_in, const int* in_sizes, int n_in,
                              void* d_out, int out_size, void* d_ws, size_t ws_size,
                              hipStream_t stream) {
    const int*  tok   = (const int*)d_in[0];
    const void* emb   = d_in[1];
    const void* w_ih0 = d_in[2];
    const void* w_hh0 = d_in[3];
    const void* b0    = d_in[4];
    const void* w_ih1 = d_in[5];
    const void* w_hh1 = d_in[6];
    const void* b1    = d_in[7];
    const void* fc1w  = d_in[8];
    const void* fc1b  = d_in[9];
    const void* fc2w  = d_in[10];
    const void* fc2b  = d_in[11];

    char* ws = (char*)d_ws;
    size_t off = 0;
    auto alloc = [&](size_t bytes) -> void* {
        void* p = ws + off; off += (bytes + 255) & ~(size_t)255; return p;
    };
    int*   flag  = (int*)alloc(256);
    u16*   Wp0   = (u16*)alloc(1024 * 320 * 2);
    u16*   Wp1   = (u16*)alloc(1024 * 256 * 2);
    u16*   Whp0  = (u16*)alloc(1024 * 128 * 2);
    u16*   Whp1  = (u16*)alloc(1024 * 128 * 2);
    float* bp0   = (float*)alloc(1024 * 4);
    float* bp1   = (float*)alloc(1024 * 4);
    float* hT    = (float*)alloc((size_t)2 * BATCH * 128 * 4);
    u16*   h0seq = (u16*)alloc((size_t)SB * 256 * 2);            // 64 MiB
    size_t gx1   = (size_t)SB * 512 * 2;                         // one dir: 128 MiB
    bool   big   = ws_size >= off + 2 * gx1;                     // both dirs resident?
    u16*   gx    = (u16*)alloc(big ? 2 * gx1 : gx1);

    k_detect<<<1, 256, 0, stream>>>((const u16*)emb, flag);

    k_packw<<<(1024 * 320 + 255) / 256, 256, 0, stream>>>(w_ih0, Wp0, 300, 320, 1024 * 320, flag);
    k_packw<<<(1024 * 256 + 255) / 256, 256, 0, stream>>>(w_ih1, Wp1, 256, 256, 1024 * 256, flag);
    k_packw<<<(1024 * 128 + 255) / 256, 256, 0, stream>>>(w_hh0, Whp0, 128, 128, 1024 * 128, flag);
    k_packw<<<(1024 * 128 + 255) / 256, 256, 0, stream>>>(w_hh1, Whp1, 128, 128, 1024 * 128, flag);
    k_packb<<<4, 256, 0, stream>>>(b0, bp0, flag);
    k_packb<<<4, 256, 0, stream>>>(b1, bp1, flag);

    if (big) {
        dim3 g(SB / 64, 16);
        k_gemm<320, true ><<<g, 256, 0, stream>>>(tok, emb, Wp0, bp0, gx, flag);
        k_lstm<true ><<<32, 1024, 0, stream>>>(gx, (size_t)SB * 512, Whp0, 0, h0seq, nullptr);
        k_gemm<256, false><<<g, 256, 0, stream>>>(nullptr, h0seq, Wp1, bp1, gx, flag);
        k_lstm<false><<<32, 1024, 0, stream>>>(gx, (size_t)SB * 512, Whp1, 0, nullptr, hT);
    } else {
        dim3 g(SB / 64, 8);   // one direction's 512 gate columns
        for (int d = 0; d < 2; ++d) {
            k_gemm<320, true ><<<g, 256, 0, stream>>>(tok, emb, Wp0 + (size_t)d * 512 * 320, bp0 + d * 512, gx, flag);
            k_lstm<true ><<<16, 1024, 0, stream>>>(gx, 0, Whp0, d, h0seq, nullptr);
        }
        for (int d = 0; d < 2; ++d) {
            k_gemm<256, false><<<g, 256, 0, stream>>>(nullptr, h0seq, Wp1 + (size_t)d * 512 * 256, bp1 + d * 512, gx, flag);
            k_lstm<false><<<16, 1024, 0, stream>>>(gx, 0, Whp1, d, nullptr, hT);
        }
    }
    k_fc<<<256, 128, 0, stream>>>(hT, fc1w, fc1b, fc2w, fc2b, d_out, flag);
}